// Round 1
// baseline (2055.298 us; speedup 1.0000x reference)
//
#include <hip/hip_runtime.h>
#include <cstdint>
#include <cstddef>

typedef unsigned int u32;
typedef unsigned long long u64;

#define NB 8192
#define BIMG 2

// ---------------- workspace layout (bytes) ----------------
// [0, 256)                     : kcount u32[BIMG] (+pad), zeroed each call
// [256, 256+131072)            : keys   u64[BIMG][NB]
// [131328, 131328+262144)      : boxes  f32[BIMG][NB][4]
// [393472, 393472+65536)       : prob   f32[BIMG][NB]
// total ~459 KB
#define WS_KCOUNT 0
#define WS_KEYS   256
#define WS_BOXES  (256 + 131072)
#define WS_PROB   (WS_BOXES + 262144)

// ---------------------------------------------------------------------------
// Kernel 1: sigmoid + box decode + sort-key build + valid count
// ---------------------------------------------------------------------------
__global__ void decode_kernel(const float* __restrict__ offsets,
                              const float* __restrict__ labels,
                              const float* __restrict__ anchors,
                              u64* __restrict__ keys,
                              float4* __restrict__ boxes,
                              float* __restrict__ prob,
                              u32* __restrict__ kcount) {
  int idx = blockIdx.x * blockDim.x + threadIdx.x;
  if (idx >= BIMG * NB) return;
  int b = idx / NB;
  int n = idx - b * NB;

  float logit = labels[idx];
  float p = 1.0f / (1.0f + expf(-logit));
  bool valid = p > 0.5f;

  const float4 an = ((const float4*)anchors)[n];   // x1,y1,x2,y2
  float acx = (an.x + an.z) / 2.0f;
  float acy = (an.y + an.w) / 2.0f;
  float aw = an.z - an.x;
  float ah = an.w - an.y;

  const float4 of = ((const float4*)offsets)[idx]; // gcx,gcy,gw,gh
  float cx = of.x * aw / 10.0f + acx;
  float cy = of.y * ah / 10.0f + acy;
  float w = expf(of.z / 5.0f) * aw;
  float h = expf(of.w / 5.0f) * ah;

  float4 bx;
  bx.x = cx - w / 2.0f;
  bx.y = cy - h / 2.0f;
  bx.z = cx + w / 2.0f;
  bx.w = cy + h / 2.0f;
  boxes[idx] = bx;
  prob[idx] = p;

  // order-preserving encode of p (p>0 always); invalid keys sink (upper=0).
  u32 e = valid ? (__float_as_uint(p) ^ 0x80000000u) : 0u;
  keys[idx] = ((u64)e << 32) | (u32)(~(u32)n);   // ~idx => ties break ascending-index

  if (valid) atomicAdd(&kcount[b], 1u);
}

// ---------------------------------------------------------------------------
// Kernel 2: per-image bitonic sort of NB u64 keys, descending (one block/image)
// ---------------------------------------------------------------------------
__global__ __launch_bounds__(1024) void sort_kernel(u64* __restrict__ keys) {
  __shared__ u64 s[NB];                 // 64 KB
  const int b = blockIdx.x;
  u64* kb = keys + (size_t)b * NB;
  for (int i = threadIdx.x; i < NB; i += 1024) s[i] = kb[i];
  __syncthreads();
  for (int k = 2; k <= NB; k <<= 1) {
    for (int j = k >> 1; j > 0; j >>= 1) {
      for (int p = threadIdx.x; p < NB / 2; p += 1024) {
        int i = ((p & ~(j - 1)) << 1) | (p & (j - 1));
        int ixj = i | j;
        u64 a = s[i];
        u64 c = s[ixj];
        bool desc = (i & k) == 0;
        if ((a < c) == desc) { s[i] = c; s[ixj] = a; }
      }
      __syncthreads();
    }
  }
  for (int i = threadIdx.x; i < NB; i += 1024) kb[i] = s[i];
}

// ---------------------------------------------------------------------------
// Kernel 3: greedy NMS (sequential over sorted order, parallel over j) + output
// One block per image. Boxes live in LDS (128 KB), suppression flags as bytes.
// ---------------------------------------------------------------------------
__global__ __launch_bounds__(1024) void nms_kernel(const u64* __restrict__ keys,
                                                   const float4* __restrict__ boxes,
                                                   const float* __restrict__ prob,
                                                   const u32* __restrict__ kcount,
                                                   float* __restrict__ out) {
  __shared__ float4 sb[NB];               // 128 KB sorted boxes
  __shared__ unsigned char flag[NB];      // 8 KB   1 = suppressed
  const int b = blockIdx.x;
  const int t = threadIdx.x;
  const u64* kb = keys + (size_t)b * NB;
  const float4* bx = boxes + (size_t)b * NB;
  const int K = (int)kcount[b];

  for (int p = t; p < NB; p += 1024) {
    u32 idx = (u32)(~kb[p]);              // recover original anchor index
    sb[p] = bx[idx];
    flag[p] = (p < K) ? (unsigned char)0 : (unsigned char)1;
  }
  __syncthreads();

  for (int i = 0; i < K; ++i) {
    if (flag[i]) continue;                // uniform across block
    float4 bi = sb[i];
    float area_i = (bi.z - bi.x) * (bi.w - bi.y);
    for (int j = i + 1 + t; j < K; j += 1024) {
      float4 bj = sb[j];
      float lx = fmaxf(bi.x, bj.x);
      float ly = fmaxf(bi.y, bj.y);
      float rx = fminf(bi.z, bj.z);
      float ry = fminf(bi.w, bj.w);
      float iw = fmaxf(rx - lx, 0.0f);
      float ih = fmaxf(ry - ly, 0.0f);
      float inter = iw * ih;
      float area_j = (bj.z - bj.x) * (bj.w - bj.y);
      float iou = inter / (area_i + area_j - inter);
      if (iou > 0.5f) flag[j] = (unsigned char)1;
    }
    __syncthreads();
  }

  // fused output: boxes [BIMG][NB][4], scores [BIMG][NB], keep [BIMG][NB]
  float4* oboxes = (float4*)(out) + (size_t)b * NB;
  float* oscores = out + (size_t)BIMG * NB * 4 + (size_t)b * NB;
  float* okeep   = out + (size_t)BIMG * NB * 5 + (size_t)b * NB;
  const float* pb = prob + (size_t)b * NB;
  for (int p = t; p < NB; p += 1024) {
    bool kp = (p < K) && (flag[p] == 0);
    float4 bv = sb[p];
    if (!kp) { bv.x = 0.0f; bv.y = 0.0f; bv.z = 0.0f; bv.w = 0.0f; }
    oboxes[p] = bv;
    u32 idx = (u32)(~kb[p]);
    oscores[p] = kp ? pb[idx] : 0.0f;
    okeep[p] = kp ? 1.0f : 0.0f;
  }
}

// ---------------------------------------------------------------------------
extern "C" void kernel_launch(void* const* d_in, const int* in_sizes, int n_in,
                              void* d_out, int out_size, void* d_ws, size_t ws_size,
                              hipStream_t stream) {
  const float* offsets = (const float*)d_in[0];   // [B,N,4] f32
  const float* labels  = (const float*)d_in[1];   // [B,N,1] f32
  const float* anchors = (const float*)d_in[2];   // [N,4]   f32
  float* out = (float*)d_out;

  char* ws = (char*)d_ws;
  u32*    kcount = (u32*)(ws + WS_KCOUNT);
  u64*    keys   = (u64*)(ws + WS_KEYS);
  float4* boxes  = (float4*)(ws + WS_BOXES);
  float*  prob   = (float*)(ws + WS_PROB);

  hipMemsetAsync(kcount, 0, 256, stream);

  int total = BIMG * NB;
  decode_kernel<<<(total + 255) / 256, 256, 0, stream>>>(
      offsets, labels, anchors, keys, boxes, prob, kcount);

  sort_kernel<<<BIMG, 1024, 0, stream>>>(keys);

  nms_kernel<<<BIMG, 1024, 0, stream>>>(keys, boxes, prob, kcount, out);
}

// Round 2
// 1476.146 us; speedup vs baseline: 1.3923x; 1.3923x over previous
//
#include <hip/hip_runtime.h>
#include <cstdint>
#include <cstddef>

typedef unsigned int u32;
typedef unsigned long long u64;

#define NB 8192
#define BIMG 2
#define WPR (NB / 64)   // 128 u64 words per mask row

// ---------------- workspace layout (bytes) ----------------
#define WS_KCOUNT 0
#define WS_KEYS   256
#define WS_BOXES  (WS_KEYS + BIMG * NB * 8)          // 131328
#define WS_PROB   (WS_BOXES + BIMG * NB * 16)        // 393472
#define WS_SBOXES (WS_PROB + BIMG * NB * 4)          // 459008
#define WS_SPROB  (WS_SBOXES + BIMG * NB * 16)       // 721152
#define WS_REMV   (WS_SPROB + BIMG * NB * 4)         // 786688
#define WS_MASK   (WS_REMV + BIMG * WPR * 8 + 256)   // 788992 (pad)
#define WS_NEEDED (WS_MASK + (size_t)BIMG * NB * WPR * 8)  // ~17.6 MB

// ---------------------------------------------------------------------------
// Kernel 1: sigmoid + box decode + sort-key build + valid count
// ---------------------------------------------------------------------------
__global__ void decode_kernel(const float* __restrict__ offsets,
                              const float* __restrict__ labels,
                              const float* __restrict__ anchors,
                              u64* __restrict__ keys,
                              float4* __restrict__ boxes,
                              float* __restrict__ prob,
                              u32* __restrict__ kcount) {
  int idx = blockIdx.x * blockDim.x + threadIdx.x;
  if (idx >= BIMG * NB) return;
  int b = idx / NB;
  int n = idx - b * NB;

  float logit = labels[idx];
  float p = 1.0f / (1.0f + expf(-logit));
  bool valid = p > 0.5f;

  const float4 an = ((const float4*)anchors)[n];   // x1,y1,x2,y2
  float acx = (an.x + an.z) / 2.0f;
  float acy = (an.y + an.w) / 2.0f;
  float aw = an.z - an.x;
  float ah = an.w - an.y;

  const float4 of = ((const float4*)offsets)[idx]; // gcx,gcy,gw,gh
  float cx = of.x * aw / 10.0f + acx;
  float cy = of.y * ah / 10.0f + acy;
  float w = expf(of.z / 5.0f) * aw;
  float h = expf(of.w / 5.0f) * ah;

  float4 bx;
  bx.x = cx - w / 2.0f;
  bx.y = cy - h / 2.0f;
  bx.z = cx + w / 2.0f;
  bx.w = cy + h / 2.0f;
  boxes[idx] = bx;
  prob[idx] = p;

  u32 e = valid ? (__float_as_uint(p) ^ 0x80000000u) : 0u;
  keys[idx] = ((u64)e << 32) | (u32)(~(u32)n);

  if (valid) atomicAdd(&kcount[b], 1u);
}

// ---------------------------------------------------------------------------
// Kernel 2: per-image bitonic sort of NB u64 keys, descending (one block/image)
// ---------------------------------------------------------------------------
__global__ __launch_bounds__(1024) void sort_kernel(u64* __restrict__ keys) {
  __shared__ u64 s[NB];                 // 64 KB
  const int b = blockIdx.x;
  u64* kb = keys + (size_t)b * NB;
  for (int i = threadIdx.x; i < NB; i += 1024) s[i] = kb[i];
  __syncthreads();
  for (int k = 2; k <= NB; k <<= 1) {
    for (int j = k >> 1; j > 0; j >>= 1) {
      for (int p = threadIdx.x; p < NB / 2; p += 1024) {
        int i = ((p & ~(j - 1)) << 1) | (p & (j - 1));
        int ixj = i | j;
        u64 a = s[i];
        u64 c = s[ixj];
        bool desc = (i & k) == 0;
        if ((a < c) == desc) { s[i] = c; s[ixj] = a; }
      }
      __syncthreads();
    }
  }
  for (int i = threadIdx.x; i < NB; i += 1024) kb[i] = s[i];
}

// ---------------------------------------------------------------------------
// Kernel 3: gather boxes/scores into sorted order (contiguous for mask build)
// ---------------------------------------------------------------------------
__global__ void reorder_kernel(const u64* __restrict__ keys,
                               const float4* __restrict__ boxes,
                               const float* __restrict__ prob,
                               float4* __restrict__ sboxes,
                               float* __restrict__ sprob) {
  int idx = blockIdx.x * blockDim.x + threadIdx.x;
  if (idx >= BIMG * NB) return;
  int b = idx / NB;
  u32 oi = (u32)(~keys[idx]);
  sboxes[idx] = boxes[(size_t)b * NB + oi];
  sprob[idx]  = prob[(size_t)b * NB + oi];
}

// ---------------------------------------------------------------------------
// Kernel 4: overlap bitmask build. One block per (sorted row, image).
// mask[b][i][w] bit l = (j=64w+l) > i && j < K && IoU(i,j) > 0.5
// ---------------------------------------------------------------------------
__global__ __launch_bounds__(256) void mask_kernel(const float4* __restrict__ sboxes,
                                                   const u32* __restrict__ kcount,
                                                   u64* __restrict__ mask) {
  const int i = blockIdx.x;       // sorted row
  const int b = blockIdx.y;
  const int K = (int)kcount[b];
  if (i >= K) return;
  const int wave = threadIdx.x >> 6;
  const int lane = threadIdx.x & 63;
  const float4* sb = sboxes + (size_t)b * NB;
  const float4 bi = sb[i];
  const float area_i = (bi.z - bi.x) * (bi.w - bi.y);
  u64* mrow = mask + ((size_t)b * NB + i) * WPR;
  for (int pass = 0; pass < WPR / 4; ++pass) {
    int w = pass * 4 + wave;
    u64 word = 0;
    if ((w + 1) * 64 > i && w * 64 < K) {   // uniform per wave
      int j = w * 64 + lane;                // j < NB always
      float4 bj = sb[j];
      float lx = fmaxf(bi.x, bj.x);
      float ly = fmaxf(bi.y, bj.y);
      float rx = fminf(bi.z, bj.z);
      float ry = fminf(bi.w, bj.w);
      float iw = fmaxf(rx - lx, 0.0f);
      float ih = fmaxf(ry - ly, 0.0f);
      float inter = iw * ih;
      float area_j = (bj.z - bj.x) * (bj.w - bj.y);
      float iou = inter / (area_i + area_j - inter);
      bool pred = (j > i) && (j < K) && (iou > 0.5f);
      word = __ballot(pred);
    }
    if (lane == 0) mrow[w] = word;
  }
}

// ---------------------------------------------------------------------------
// Kernel 5: serial greedy scan, 1 wave per image, no barriers.
// Lane l owns remv words 2l and 2l+1 (covers 8192 bits).
// ---------------------------------------------------------------------------
__device__ inline u64 rdl64(u64 v, int lane) {
  u32 lo = (u32)__builtin_amdgcn_readlane((int)(u32)v, lane);
  u32 hi = (u32)__builtin_amdgcn_readlane((int)(u32)(v >> 32), lane);
  return ((u64)hi << 32) | lo;
}

__global__ __launch_bounds__(64) void scan_kernel(const u64* __restrict__ mask,
                                                  const u32* __restrict__ kcount,
                                                  u64* __restrict__ remv) {
  const int b = blockIdx.x;
  const int lid = threadIdx.x;
  const int K = (int)kcount[b];
  const u64* mb = mask + (size_t)b * NB * WPR;
  u64 r0 = 0, r1 = 0;

  ulonglong2 buf[8];                       // 8-deep row prefetch (static idx after unroll)
#pragma unroll
  for (int q = 0; q < 8; ++q) {
    buf[q] = ((const ulonglong2*)(mb + (size_t)q * WPR))[lid];
  }

  for (int c = 0; c < WPR; ++c) {
    if (c * 64 >= K) break;
    const int owner = c >> 1;
    u64 r = rdl64((c & 1) ? r1 : r0, owner);   // replicated current-chunk word
#pragma unroll
    for (int l = 0; l < 64; ++l) {
      int i = c * 64 + l;
      if (i >= K) break;
      ulonglong2 cur = buf[l & 7];
      int ip = (i + 8 < NB) ? (i + 8) : (NB - 1);
      buf[l & 7] = ((const ulonglong2*)(mb + (size_t)ip * WPR))[lid];
      u64 slot = (c & 1) ? cur.y : cur.x;
      u64 cw = rdl64(slot, owner);             // row i's chunk word (off-chain)
      if (((r >> l) & 1ull) == 0ull) {         // kept (uniform)
        r  |= cw;
        r0 |= cur.x;
        r1 |= cur.y;
      }
    }
  }
  remv[(size_t)b * WPR + 2 * lid]     = r0;
  remv[(size_t)b * WPR + 2 * lid + 1] = r1;
}

// ---------------------------------------------------------------------------
// Kernel 6: output write
// ---------------------------------------------------------------------------
__global__ void output_kernel(const float4* __restrict__ sboxes,
                              const float* __restrict__ sprob,
                              const u64* __restrict__ remv,
                              const u32* __restrict__ kcount,
                              float* __restrict__ out) {
  int idx = blockIdx.x * blockDim.x + threadIdx.x;
  if (idx >= BIMG * NB) return;
  int b = idx / NB;
  int p = idx - b * NB;
  int K = (int)kcount[b];
  u64 w = remv[(size_t)b * WPR + (p >> 6)];
  bool kp = (p < K) && !((w >> (p & 63)) & 1ull);
  float4 bv = sboxes[idx];
  if (!kp) { bv.x = 0.0f; bv.y = 0.0f; bv.z = 0.0f; bv.w = 0.0f; }
  ((float4*)out)[idx] = bv;
  out[(size_t)BIMG * NB * 4 + idx] = kp ? sprob[idx] : 0.0f;
  out[(size_t)BIMG * NB * 5 + idx] = kp ? 1.0f : 0.0f;
}

// ---------------------------------------------------------------------------
// Fallback (round-0) NMS kernel, used only if workspace is too small
// ---------------------------------------------------------------------------
__global__ __launch_bounds__(1024) void nms_kernel(const u64* __restrict__ keys,
                                                   const float4* __restrict__ boxes,
                                                   const float* __restrict__ prob,
                                                   const u32* __restrict__ kcount,
                                                   float* __restrict__ out) {
  __shared__ float4 sb[NB];
  __shared__ unsigned char flag[NB];
  const int b = blockIdx.x;
  const int t = threadIdx.x;
  const u64* kb = keys + (size_t)b * NB;
  const float4* bx = boxes + (size_t)b * NB;
  const int K = (int)kcount[b];

  for (int p = t; p < NB; p += 1024) {
    u32 idx = (u32)(~kb[p]);
    sb[p] = bx[idx];
    flag[p] = (p < K) ? (unsigned char)0 : (unsigned char)1;
  }
  __syncthreads();

  for (int i = 0; i < K; ++i) {
    if (flag[i]) continue;
    float4 bi = sb[i];
    float area_i = (bi.z - bi.x) * (bi.w - bi.y);
    for (int j = i + 1 + t; j < K; j += 1024) {
      float4 bj = sb[j];
      float lx = fmaxf(bi.x, bj.x);
      float ly = fmaxf(bi.y, bj.y);
      float rx = fminf(bi.z, bj.z);
      float ry = fminf(bi.w, bj.w);
      float iw = fmaxf(rx - lx, 0.0f);
      float ih = fmaxf(ry - ly, 0.0f);
      float inter = iw * ih;
      float area_j = (bj.z - bj.x) * (bj.w - bj.y);
      float iou = inter / (area_i + area_j - inter);
      if (iou > 0.5f) flag[j] = (unsigned char)1;
    }
    __syncthreads();
  }

  float4* oboxes = (float4*)(out) + (size_t)b * NB;
  float* oscores = out + (size_t)BIMG * NB * 4 + (size_t)b * NB;
  float* okeep   = out + (size_t)BIMG * NB * 5 + (size_t)b * NB;
  const float* pb = prob + (size_t)b * NB;
  for (int p = t; p < NB; p += 1024) {
    bool kp = (p < K) && (flag[p] == 0);
    float4 bv = sb[p];
    if (!kp) { bv.x = 0.0f; bv.y = 0.0f; bv.z = 0.0f; bv.w = 0.0f; }
    oboxes[p] = bv;
    u32 idx = (u32)(~kb[p]);
    oscores[p] = kp ? pb[idx] : 0.0f;
    okeep[p] = kp ? 1.0f : 0.0f;
  }
}

// ---------------------------------------------------------------------------
extern "C" void kernel_launch(void* const* d_in, const int* in_sizes, int n_in,
                              void* d_out, int out_size, void* d_ws, size_t ws_size,
                              hipStream_t stream) {
  const float* offsets = (const float*)d_in[0];   // [B,N,4] f32
  const float* labels  = (const float*)d_in[1];   // [B,N,1] f32
  const float* anchors = (const float*)d_in[2];   // [N,4]   f32
  float* out = (float*)d_out;

  char* ws = (char*)d_ws;
  u32*    kcount = (u32*)(ws + WS_KCOUNT);
  u64*    keys   = (u64*)(ws + WS_KEYS);
  float4* boxes  = (float4*)(ws + WS_BOXES);
  float*  prob   = (float*)(ws + WS_PROB);

  hipMemsetAsync(kcount, 0, 256, stream);

  int total = BIMG * NB;
  decode_kernel<<<(total + 255) / 256, 256, 0, stream>>>(
      offsets, labels, anchors, keys, boxes, prob, kcount);

  sort_kernel<<<BIMG, 1024, 0, stream>>>(keys);

  if (ws_size >= WS_NEEDED) {
    float4* sboxes = (float4*)(ws + WS_SBOXES);
    float*  sprob  = (float*)(ws + WS_SPROB);
    u64*    remv   = (u64*)(ws + WS_REMV);
    u64*    mask   = (u64*)(ws + WS_MASK);

    reorder_kernel<<<(total + 255) / 256, 256, 0, stream>>>(
        keys, boxes, prob, sboxes, sprob);

    mask_kernel<<<dim3(NB, BIMG), 256, 0, stream>>>(sboxes, kcount, mask);

    scan_kernel<<<BIMG, 64, 0, stream>>>(mask, kcount, remv);

    output_kernel<<<(total + 255) / 256, 256, 0, stream>>>(
        sboxes, sprob, remv, kcount, out);
  } else {
    nms_kernel<<<BIMG, 1024, 0, stream>>>(keys, boxes, prob, kcount, out);
  }
}

// Round 3
// 315.621 us; speedup vs baseline: 6.5119x; 4.6770x over previous
//
#include <hip/hip_runtime.h>
#include <cstdint>
#include <cstddef>

typedef unsigned int u32;
typedef unsigned long long u64;

#define NB 8192
#define BIMG 2
#define WPR (NB / 64)   // 128 u64 words per mask row

// ---------------- workspace layout (bytes) ----------------
#define WS_KCOUNT 0
#define WS_KEYS   256
#define WS_BOXES  (WS_KEYS + BIMG * NB * 8)          // 131328
#define WS_PROB   (WS_BOXES + BIMG * NB * 16)        // 393472
#define WS_SBOXES (WS_PROB + BIMG * NB * 4)          // 459008
#define WS_SPROB  (WS_SBOXES + BIMG * NB * 16)       // 721152
#define WS_REMV   (WS_SPROB + BIMG * NB * 4)         // 786688
#define WS_MASK   (WS_REMV + BIMG * WPR * 8 + 256)   // 788992 (pad)
#define WS_ROWNZ  (WS_MASK + (size_t)BIMG * NB * WPR * 8)
#define WS_NEEDED (WS_ROWNZ + (size_t)BIMG * NB)     // ~17.6 MB

// ---------------------------------------------------------------------------
// Kernel 1: sigmoid + box decode + sort-key build + valid count
// ---------------------------------------------------------------------------
__global__ void decode_kernel(const float* __restrict__ offsets,
                              const float* __restrict__ labels,
                              const float* __restrict__ anchors,
                              u64* __restrict__ keys,
                              float4* __restrict__ boxes,
                              float* __restrict__ prob,
                              u32* __restrict__ kcount) {
  int idx = blockIdx.x * blockDim.x + threadIdx.x;
  if (idx >= BIMG * NB) return;
  int b = idx / NB;
  int n = idx - b * NB;

  float logit = labels[idx];
  float p = 1.0f / (1.0f + expf(-logit));
  bool valid = p > 0.5f;

  const float4 an = ((const float4*)anchors)[n];   // x1,y1,x2,y2
  float acx = (an.x + an.z) / 2.0f;
  float acy = (an.y + an.w) / 2.0f;
  float aw = an.z - an.x;
  float ah = an.w - an.y;

  const float4 of = ((const float4*)offsets)[idx]; // gcx,gcy,gw,gh
  float cx = of.x * aw / 10.0f + acx;
  float cy = of.y * ah / 10.0f + acy;
  float w = expf(of.z / 5.0f) * aw;
  float h = expf(of.w / 5.0f) * ah;

  float4 bx;
  bx.x = cx - w / 2.0f;
  bx.y = cy - h / 2.0f;
  bx.z = cx + w / 2.0f;
  bx.w = cy + h / 2.0f;
  boxes[idx] = bx;
  prob[idx] = p;

  u32 e = valid ? (__float_as_uint(p) ^ 0x80000000u) : 0u;
  keys[idx] = ((u64)e << 32) | (u32)(~(u32)n);

  if (valid) atomicAdd(&kcount[b], 1u);
}

// ---------------------------------------------------------------------------
// Kernel 2: per-image bitonic sort of NB u64 keys, descending (one block/image)
// ---------------------------------------------------------------------------
__global__ __launch_bounds__(1024) void sort_kernel(u64* __restrict__ keys) {
  __shared__ u64 s[NB];                 // 64 KB
  const int b = blockIdx.x;
  u64* kb = keys + (size_t)b * NB;
  for (int i = threadIdx.x; i < NB; i += 1024) s[i] = kb[i];
  __syncthreads();
  for (int k = 2; k <= NB; k <<= 1) {
    for (int j = k >> 1; j > 0; j >>= 1) {
      for (int p = threadIdx.x; p < NB / 2; p += 1024) {
        int i = ((p & ~(j - 1)) << 1) | (p & (j - 1));
        int ixj = i | j;
        u64 a = s[i];
        u64 c = s[ixj];
        bool desc = (i & k) == 0;
        if ((a < c) == desc) { s[i] = c; s[ixj] = a; }
      }
      __syncthreads();
    }
  }
  for (int i = threadIdx.x; i < NB; i += 1024) kb[i] = s[i];
}

// ---------------------------------------------------------------------------
// Kernel 3: gather boxes/scores into sorted order
// ---------------------------------------------------------------------------
__global__ void reorder_kernel(const u64* __restrict__ keys,
                               const float4* __restrict__ boxes,
                               const float* __restrict__ prob,
                               float4* __restrict__ sboxes,
                               float* __restrict__ sprob) {
  int idx = blockIdx.x * blockDim.x + threadIdx.x;
  if (idx >= BIMG * NB) return;
  int b = idx / NB;
  u32 oi = (u32)(~keys[idx]);
  sboxes[idx] = boxes[(size_t)b * NB + oi];
  sprob[idx]  = prob[(size_t)b * NB + oi];
}

// ---------------------------------------------------------------------------
// Kernel 4: overlap bitmask build + per-row nonzero flag.
// mask[b][i][w] bit l = (j=64w+l) > i && j < K && IoU(i,j) > 0.5
// ---------------------------------------------------------------------------
__global__ __launch_bounds__(256) void mask_kernel(const float4* __restrict__ sboxes,
                                                   const u32* __restrict__ kcount,
                                                   u64* __restrict__ mask,
                                                   unsigned char* __restrict__ rownz) {
  const int i = blockIdx.x;       // sorted row
  const int b = blockIdx.y;
  const int K = (int)kcount[b];
  if (i >= K) return;
  const int wave = threadIdx.x >> 6;
  const int lane = threadIdx.x & 63;
  __shared__ u32 anyf[4];
  const float4* sb = sboxes + (size_t)b * NB;
  const float4 bi = sb[i];
  const float area_i = (bi.z - bi.x) * (bi.w - bi.y);
  u64* mrow = mask + ((size_t)b * NB + i) * WPR;
  bool any = false;
  for (int pass = 0; pass < WPR / 4; ++pass) {
    int w = pass * 4 + wave;
    u64 word = 0;
    if ((w + 1) * 64 > i && w * 64 < K) {   // uniform per wave
      int j = w * 64 + lane;
      float4 bj = sb[j];
      float lx = fmaxf(bi.x, bj.x);
      float ly = fmaxf(bi.y, bj.y);
      float rx = fminf(bi.z, bj.z);
      float ry = fminf(bi.w, bj.w);
      float iw = fmaxf(rx - lx, 0.0f);
      float ih = fmaxf(ry - ly, 0.0f);
      float inter = iw * ih;
      float area_j = (bj.z - bj.x) * (bj.w - bj.y);
      float iou = inter / (area_i + area_j - inter);
      bool pred = (j > i) && (j < K) && (iou > 0.5f);
      word = __ballot(pred);
      any = any || (word != 0ull);
    }
    if (lane == 0) mrow[w] = word;
  }
  if (lane == 0) anyf[wave] = any ? 1u : 0u;
  __syncthreads();
  if (threadIdx.x == 0) {
    u32 a = anyf[0] | anyf[1] | anyf[2] | anyf[3];
    rownz[(size_t)b * NB + i] = (unsigned char)(a ? 1 : 0);
  }
}

// ---------------------------------------------------------------------------
// Kernel 5: chunked greedy scan, 1 wave per image.
// Lane l owns remv words 2l, 2l+1. Per 64-bit chunk: resolve diagonal block
// serially (SALU over nonzero rows only), then OR kept rows' full masks in
// groups of 16 independent loads.
// ---------------------------------------------------------------------------
__device__ inline u64 rdl64(u64 v, int lane) {
  u32 lo = (u32)__builtin_amdgcn_readlane((int)(u32)v, lane);
  u32 hi = (u32)__builtin_amdgcn_readlane((int)(u32)(v >> 32), lane);
  return ((u64)hi << 32) | lo;
}

__global__ __launch_bounds__(64) void scan_kernel(const u64* __restrict__ mask,
                                                  const unsigned char* __restrict__ rownz,
                                                  const u32* __restrict__ kcount,
                                                  u64* __restrict__ remv) {
  const int b = blockIdx.x;
  const int lid = threadIdx.x;
  const int K = (int)kcount[b];
  const u64* mb = mask + (size_t)b * NB * WPR;
  const unsigned char* nzb = rownz + (size_t)b * NB;

  // init remv: bits >= K are suppressed from the start
  u64 r0, r1;
  {
    int w0 = 2 * lid, w1 = 2 * lid + 1;
    int lo0 = w0 * 64, lo1 = w1 * 64;
    r0 = (lo0 + 64 <= K) ? 0ull : ((lo0 >= K) ? ~0ull : ((~0ull) << (K - lo0)));
    r1 = (lo1 + 64 <= K) ? 0ull : ((lo1 >= K) ? ~0ull : ((~0ull) << (K - lo1)));
  }

  const int NC = min(WPR, (K + 63) >> 6);

  // diagonal block for chunk 0
  u64 dw = 0;
  if (NC > 0) dw = (lid < K) ? mb[(size_t)lid * WPR + 0] : 0ull;

  for (int c = 0; c < NC; ++c) {
    // prefetch next chunk's diagonal block
    u64 dw_next = 0;
    if (c + 1 < NC) {
      int i = (c + 1) * 64 + lid;
      dw_next = (i < K) ? mb[(size_t)i * WPR + (c + 1)] : 0ull;
    }
    // per-row "has any suppression bits" word for this chunk
    unsigned char nzbyte = nzb[c * 64 + lid];
    u64 nzword = __ballot(nzbyte != 0);

    const int owner = c >> 1;
    u64 rc = rdl64((c & 1) ? r1 : r0, owner);   // current suppressed word (uniform)

    // within-chunk resolution: ascending order over rows with nonzero diag word
    u64 nzd = __ballot(dw != 0ull);
    while (nzd) {
      int l = __builtin_ctzll(nzd);
      nzd &= nzd - 1;
      if (((rc >> l) & 1ull) == 0ull) {
        rc |= rdl64(dw, l);
      }
    }
    if (lid == owner) { if (c & 1) r1 = rc; else r0 = rc; }

    // OR full mask rows of kept boxes (that have any bits) into distributed remv
    u64 ku = (~rc) & nzword;
    while (ku) {
      int last = __builtin_ctzll(ku);
      u64 kk = ku;
      ulonglong2 v[16];
#pragma unroll
      for (int q = 0; q < 16; ++q) {
        int l = kk ? __builtin_ctzll(kk) : last;   // pad with duplicate (idempotent OR)
        if (kk) kk &= kk - 1;
        int i = c * 64 + l;
        v[q] = ((const ulonglong2*)(mb + (size_t)i * WPR))[lid];
      }
      ku = kk;
#pragma unroll
      for (int q = 0; q < 16; ++q) { r0 |= v[q].x; r1 |= v[q].y; }
    }
    dw = dw_next;
  }
  remv[(size_t)b * WPR + 2 * lid]     = r0;
  remv[(size_t)b * WPR + 2 * lid + 1] = r1;
}

// ---------------------------------------------------------------------------
// Kernel 6: output write
// ---------------------------------------------------------------------------
__global__ void output_kernel(const float4* __restrict__ sboxes,
                              const float* __restrict__ sprob,
                              const u64* __restrict__ remv,
                              const u32* __restrict__ kcount,
                              float* __restrict__ out) {
  int idx = blockIdx.x * blockDim.x + threadIdx.x;
  if (idx >= BIMG * NB) return;
  int b = idx / NB;
  int p = idx - b * NB;
  int K = (int)kcount[b];
  u64 w = remv[(size_t)b * WPR + (p >> 6)];
  bool kp = (p < K) && !((w >> (p & 63)) & 1ull);
  float4 bv = sboxes[idx];
  if (!kp) { bv.x = 0.0f; bv.y = 0.0f; bv.z = 0.0f; bv.w = 0.0f; }
  ((float4*)out)[idx] = bv;
  out[(size_t)BIMG * NB * 4 + idx] = kp ? sprob[idx] : 0.0f;
  out[(size_t)BIMG * NB * 5 + idx] = kp ? 1.0f : 0.0f;
}

// ---------------------------------------------------------------------------
// Fallback (round-0) NMS kernel, used only if workspace is too small
// ---------------------------------------------------------------------------
__global__ __launch_bounds__(1024) void nms_kernel(const u64* __restrict__ keys,
                                                   const float4* __restrict__ boxes,
                                                   const float* __restrict__ prob,
                                                   const u32* __restrict__ kcount,
                                                   float* __restrict__ out) {
  __shared__ float4 sb[NB];
  __shared__ unsigned char flag[NB];
  const int b = blockIdx.x;
  const int t = threadIdx.x;
  const u64* kb = keys + (size_t)b * NB;
  const float4* bx = boxes + (size_t)b * NB;
  const int K = (int)kcount[b];

  for (int p = t; p < NB; p += 1024) {
    u32 idx = (u32)(~kb[p]);
    sb[p] = bx[idx];
    flag[p] = (p < K) ? (unsigned char)0 : (unsigned char)1;
  }
  __syncthreads();

  for (int i = 0; i < K; ++i) {
    if (flag[i]) continue;
    float4 bi = sb[i];
    float area_i = (bi.z - bi.x) * (bi.w - bi.y);
    for (int j = i + 1 + t; j < K; j += 1024) {
      float4 bj = sb[j];
      float lx = fmaxf(bi.x, bj.x);
      float ly = fmaxf(bi.y, bj.y);
      float rx = fminf(bi.z, bj.z);
      float ry = fminf(bi.w, bj.w);
      float iw = fmaxf(rx - lx, 0.0f);
      float ih = fmaxf(ry - ly, 0.0f);
      float inter = iw * ih;
      float area_j = (bj.z - bj.x) * (bj.w - bj.y);
      float iou = inter / (area_i + area_j - inter);
      if (iou > 0.5f) flag[j] = (unsigned char)1;
    }
    __syncthreads();
  }

  float4* oboxes = (float4*)(out) + (size_t)b * NB;
  float* oscores = out + (size_t)BIMG * NB * 4 + (size_t)b * NB;
  float* okeep   = out + (size_t)BIMG * NB * 5 + (size_t)b * NB;
  const float* pb = prob + (size_t)b * NB;
  for (int p = t; p < NB; p += 1024) {
    bool kp = (p < K) && (flag[p] == 0);
    float4 bv = sb[p];
    if (!kp) { bv.x = 0.0f; bv.y = 0.0f; bv.z = 0.0f; bv.w = 0.0f; }
    oboxes[p] = bv;
    u32 idx = (u32)(~kb[p]);
    oscores[p] = kp ? pb[idx] : 0.0f;
    okeep[p] = kp ? 1.0f : 0.0f;
  }
}

// ---------------------------------------------------------------------------
extern "C" void kernel_launch(void* const* d_in, const int* in_sizes, int n_in,
                              void* d_out, int out_size, void* d_ws, size_t ws_size,
                              hipStream_t stream) {
  const float* offsets = (const float*)d_in[0];   // [B,N,4] f32
  const float* labels  = (const float*)d_in[1];   // [B,N,1] f32
  const float* anchors = (const float*)d_in[2];   // [N,4]   f32
  float* out = (float*)d_out;

  char* ws = (char*)d_ws;
  u32*    kcount = (u32*)(ws + WS_KCOUNT);
  u64*    keys   = (u64*)(ws + WS_KEYS);
  float4* boxes  = (float4*)(ws + WS_BOXES);
  float*  prob   = (float*)(ws + WS_PROB);

  hipMemsetAsync(kcount, 0, 256, stream);

  int total = BIMG * NB;
  decode_kernel<<<(total + 255) / 256, 256, 0, stream>>>(
      offsets, labels, anchors, keys, boxes, prob, kcount);

  sort_kernel<<<BIMG, 1024, 0, stream>>>(keys);

  if (ws_size >= WS_NEEDED) {
    float4* sboxes = (float4*)(ws + WS_SBOXES);
    float*  sprob  = (float*)(ws + WS_SPROB);
    u64*    remv   = (u64*)(ws + WS_REMV);
    u64*    mask   = (u64*)(ws + WS_MASK);
    unsigned char* rownz = (unsigned char*)(ws + WS_ROWNZ);

    reorder_kernel<<<(total + 255) / 256, 256, 0, stream>>>(
        keys, boxes, prob, sboxes, sprob);

    mask_kernel<<<dim3(NB, BIMG), 256, 0, stream>>>(sboxes, kcount, mask, rownz);

    scan_kernel<<<BIMG, 64, 0, stream>>>(mask, rownz, kcount, remv);

    output_kernel<<<(total + 255) / 256, 256, 0, stream>>>(
        sboxes, sprob, remv, kcount, out);
  } else {
    nms_kernel<<<BIMG, 1024, 0, stream>>>(keys, boxes, prob, kcount, out);
  }
}

// Round 4
// 229.106 us; speedup vs baseline: 8.9710x; 1.3776x over previous
//
#include <hip/hip_runtime.h>
#include <cstdint>
#include <cstddef>

typedef unsigned int u32;
typedef unsigned long long u64;

#define NB 8192
#define BIMG 2
#define WPR (NB / 64)   // 128 u64 words per mask row

// ---------------- workspace layout (bytes) ----------------
#define WS_KCOUNT 0
#define WS_KEYS   256
#define WS_BOXES  (WS_KEYS + BIMG * NB * 8)          // 131328
#define WS_PROB   (WS_BOXES + BIMG * NB * 16)        // 393472
#define WS_SBOXES (WS_PROB + BIMG * NB * 4)          // 459008
#define WS_SPROB  (WS_SBOXES + BIMG * NB * 16)       // 721152
#define WS_REMV   (WS_SPROB + BIMG * NB * 4)         // 786688
#define WS_MASK   (WS_REMV + BIMG * WPR * 8 + 256)   // 788992 (pad)
#define WS_ROWNZ  (WS_MASK + (size_t)BIMG * NB * WPR * 8)
#define WS_NEEDED (WS_ROWNZ + (size_t)BIMG * NB)     // ~17.6 MB

// ---------------------------------------------------------------------------
// Kernel 1: sigmoid + box decode + sort-key build (NO atomics)
// ---------------------------------------------------------------------------
__global__ void decode_kernel(const float* __restrict__ offsets,
                              const float* __restrict__ labels,
                              const float* __restrict__ anchors,
                              u64* __restrict__ keys,
                              float4* __restrict__ boxes,
                              float* __restrict__ prob) {
  int idx = blockIdx.x * blockDim.x + threadIdx.x;
  if (idx >= BIMG * NB) return;
  int b = idx / NB;
  int n = idx - b * NB;
  (void)b;

  float logit = labels[idx];
  float p = 1.0f / (1.0f + expf(-logit));
  bool valid = p > 0.5f;

  const float4 an = ((const float4*)anchors)[n];   // x1,y1,x2,y2
  float acx = (an.x + an.z) / 2.0f;
  float acy = (an.y + an.w) / 2.0f;
  float aw = an.z - an.x;
  float ah = an.w - an.y;

  const float4 of = ((const float4*)offsets)[idx]; // gcx,gcy,gw,gh
  float cx = of.x * aw / 10.0f + acx;
  float cy = of.y * ah / 10.0f + acy;
  float w = expf(of.z / 5.0f) * aw;
  float h = expf(of.w / 5.0f) * ah;

  float4 bx;
  bx.x = cx - w / 2.0f;
  bx.y = cy - h / 2.0f;
  bx.z = cx + w / 2.0f;
  bx.w = cy + h / 2.0f;
  boxes[idx] = bx;
  prob[idx] = p;

  u32 e = valid ? (__float_as_uint(p) ^ 0x80000000u) : 0u;
  keys[idx] = ((u64)e << 32) | (u32)(~(u32)n);
}

// ---------------------------------------------------------------------------
// Kernel 2: per-image bitonic sort (desc) + valid count + fused sorted gather
// ---------------------------------------------------------------------------
__global__ __launch_bounds__(1024) void sort_kernel(u64* __restrict__ keys,
                                                    const float4* __restrict__ boxes,
                                                    const float* __restrict__ prob,
                                                    float4* __restrict__ sboxes,
                                                    float* __restrict__ sprob,
                                                    u32* __restrict__ kcount) {
  __shared__ u64 s[NB];                 // 64 KB
  __shared__ u32 scnt;
  const int b = blockIdx.x;
  u64* kb = keys + (size_t)b * NB;
  if (threadIdx.x == 0) scnt = 0;
  u32 lc = 0;
  for (int i = threadIdx.x; i < NB; i += 1024) {
    u64 k = kb[i];
    s[i] = k;
    lc += ((u32)(k >> 32) != 0u) ? 1u : 0u;
  }
  // wave reduction of local valid count
  for (int off = 32; off > 0; off >>= 1) lc += __shfl_down(lc, off, 64);
  __syncthreads();                       // scnt init + s[] loaded
  if ((threadIdx.x & 63) == 0) atomicAdd(&scnt, lc);   // 16 LDS atomics
  __syncthreads();
  if (threadIdx.x == 0) kcount[b] = scnt;

  for (int k = 2; k <= NB; k <<= 1) {
    for (int j = k >> 1; j > 0; j >>= 1) {
      for (int p = threadIdx.x; p < NB / 2; p += 1024) {
        int i = ((p & ~(j - 1)) << 1) | (p & (j - 1));
        int ixj = i | j;
        u64 a = s[i];
        u64 c = s[ixj];
        bool desc = (i & k) == 0;
        if ((a < c) == desc) { s[i] = c; s[ixj] = a; }
      }
      __syncthreads();
    }
  }

  // write back keys + fused gather into sorted order
  const float4* bx = boxes + (size_t)b * NB;
  const float* pb = prob + (size_t)b * NB;
  for (int i = threadIdx.x; i < NB; i += 1024) {
    u64 k = s[i];
    kb[i] = k;
    u32 oi = (u32)(~k);                 // original anchor index
    sboxes[(size_t)b * NB + i] = bx[oi];
    sprob[(size_t)b * NB + i]  = pb[oi];
  }
}

// ---------------------------------------------------------------------------
// Kernel 4: overlap bitmask build + per-row nonzero flag.
// mask[b][i][w] bit l = (j=64w+l) > i && j < K && IoU(i,j) > 0.5
// ---------------------------------------------------------------------------
__global__ __launch_bounds__(256) void mask_kernel(const float4* __restrict__ sboxes,
                                                   const u32* __restrict__ kcount,
                                                   u64* __restrict__ mask,
                                                   unsigned char* __restrict__ rownz) {
  const int i = blockIdx.x;       // sorted row
  const int b = blockIdx.y;
  const int K = (int)kcount[b];
  if (i >= K) return;
  const int wave = threadIdx.x >> 6;
  const int lane = threadIdx.x & 63;
  __shared__ u32 anyf[4];
  const float4* sb = sboxes + (size_t)b * NB;
  const float4 bi = sb[i];
  const float area_i = (bi.z - bi.x) * (bi.w - bi.y);
  u64* mrow = mask + ((size_t)b * NB + i) * WPR;
  bool any = false;
  for (int pass = 0; pass < WPR / 4; ++pass) {
    int w = pass * 4 + wave;
    u64 word = 0;
    if ((w + 1) * 64 > i && w * 64 < K) {   // uniform per wave
      int j = w * 64 + lane;
      float4 bj = sb[j];
      float lx = fmaxf(bi.x, bj.x);
      float ly = fmaxf(bi.y, bj.y);
      float rx = fminf(bi.z, bj.z);
      float ry = fminf(bi.w, bj.w);
      float iw = fmaxf(rx - lx, 0.0f);
      float ih = fmaxf(ry - ly, 0.0f);
      float inter = iw * ih;
      float area_j = (bj.z - bj.x) * (bj.w - bj.y);
      float iou = inter / (area_i + area_j - inter);
      bool pred = (j > i) && (j < K) && (iou > 0.5f);
      word = __ballot(pred);
      any = any || (word != 0ull);
    }
    if (lane == 0) mrow[w] = word;
  }
  if (lane == 0) anyf[wave] = any ? 1u : 0u;
  __syncthreads();
  if (threadIdx.x == 0) {
    u32 a = anyf[0] | anyf[1] | anyf[2] | anyf[3];
    rownz[(size_t)b * NB + i] = (unsigned char)(a ? 1 : 0);
  }
}

// ---------------------------------------------------------------------------
// Kernel 5: chunked greedy scan, 1 wave per image.
// ---------------------------------------------------------------------------
__device__ inline u64 rdl64(u64 v, int lane) {
  u32 lo = (u32)__builtin_amdgcn_readlane((int)(u32)v, lane);
  u32 hi = (u32)__builtin_amdgcn_readlane((int)(u32)(v >> 32), lane);
  return ((u64)hi << 32) | lo;
}

__global__ __launch_bounds__(64) void scan_kernel(const u64* __restrict__ mask,
                                                  const unsigned char* __restrict__ rownz,
                                                  const u32* __restrict__ kcount,
                                                  u64* __restrict__ remv) {
  const int b = blockIdx.x;
  const int lid = threadIdx.x;
  const int K = (int)kcount[b];
  const u64* mb = mask + (size_t)b * NB * WPR;
  const unsigned char* nzb = rownz + (size_t)b * NB;

  // init remv: bits >= K are suppressed from the start
  u64 r0, r1;
  {
    int w0 = 2 * lid, w1 = 2 * lid + 1;
    int lo0 = w0 * 64, lo1 = w1 * 64;
    r0 = (lo0 + 64 <= K) ? 0ull : ((lo0 >= K) ? ~0ull : ((~0ull) << (K - lo0)));
    r1 = (lo1 + 64 <= K) ? 0ull : ((lo1 >= K) ? ~0ull : ((~0ull) << (K - lo1)));
  }

  const int NC = min(WPR, (K + 63) >> 6);

  // diagonal block for chunk 0
  u64 dw = 0;
  if (NC > 0) dw = (lid < K) ? mb[(size_t)lid * WPR + 0] : 0ull;

  for (int c = 0; c < NC; ++c) {
    // prefetch next chunk's diagonal block
    u64 dw_next = 0;
    if (c + 1 < NC) {
      int i = (c + 1) * 64 + lid;
      dw_next = (i < K) ? mb[(size_t)i * WPR + (c + 1)] : 0ull;
    }
    // per-row "has any suppression bits" word for this chunk
    unsigned char nzbyte = nzb[c * 64 + lid];
    u64 nzword = __ballot(nzbyte != 0);

    const int owner = c >> 1;
    u64 rc = rdl64((c & 1) ? r1 : r0, owner);   // current suppressed word (uniform)

    // within-chunk resolution: ascending order over rows with nonzero diag word
    u64 nzd = __ballot(dw != 0ull);
    while (nzd) {
      int l = __builtin_ctzll(nzd);
      nzd &= nzd - 1;
      if (((rc >> l) & 1ull) == 0ull) {
        rc |= rdl64(dw, l);
      }
    }
    if (lid == owner) { if (c & 1) r1 = rc; else r0 = rc; }

    // OR full mask rows of kept boxes (that have any bits) into distributed remv
    u64 ku = (~rc) & nzword;
    while (ku) {
      int last = __builtin_ctzll(ku);
      u64 kk = ku;
      ulonglong2 v[16];
#pragma unroll
      for (int q = 0; q < 16; ++q) {
        int l = kk ? __builtin_ctzll(kk) : last;   // pad with duplicate (idempotent OR)
        if (kk) kk &= kk - 1;
        int i = c * 64 + l;
        v[q] = ((const ulonglong2*)(mb + (size_t)i * WPR))[lid];
      }
      ku = kk;
#pragma unroll
      for (int q = 0; q < 16; ++q) { r0 |= v[q].x; r1 |= v[q].y; }
    }
    dw = dw_next;
  }
  remv[(size_t)b * WPR + 2 * lid]     = r0;
  remv[(size_t)b * WPR + 2 * lid + 1] = r1;
}

// ---------------------------------------------------------------------------
// Kernel 6: output write
// ---------------------------------------------------------------------------
__global__ void output_kernel(const float4* __restrict__ sboxes,
                              const float* __restrict__ sprob,
                              const u64* __restrict__ remv,
                              const u32* __restrict__ kcount,
                              float* __restrict__ out) {
  int idx = blockIdx.x * blockDim.x + threadIdx.x;
  if (idx >= BIMG * NB) return;
  int b = idx / NB;
  int p = idx - b * NB;
  int K = (int)kcount[b];
  u64 w = remv[(size_t)b * WPR + (p >> 6)];
  bool kp = (p < K) && !((w >> (p & 63)) & 1ull);
  float4 bv = sboxes[idx];
  if (!kp) { bv.x = 0.0f; bv.y = 0.0f; bv.z = 0.0f; bv.w = 0.0f; }
  ((float4*)out)[idx] = bv;
  out[(size_t)BIMG * NB * 4 + idx] = kp ? sprob[idx] : 0.0f;
  out[(size_t)BIMG * NB * 5 + idx] = kp ? 1.0f : 0.0f;
}

// ---------------------------------------------------------------------------
// Fallback NMS kernel (used only if workspace is too small)
// ---------------------------------------------------------------------------
__global__ __launch_bounds__(1024) void nms_kernel(const u64* __restrict__ keys,
                                                   const float4* __restrict__ boxes,
                                                   const float* __restrict__ prob,
                                                   const u32* __restrict__ kcount,
                                                   float* __restrict__ out) {
  __shared__ float4 sb[NB];
  __shared__ unsigned char flag[NB];
  const int b = blockIdx.x;
  const int t = threadIdx.x;
  const u64* kb = keys + (size_t)b * NB;
  const float4* bx = boxes + (size_t)b * NB;
  const int K = (int)kcount[b];

  for (int p = t; p < NB; p += 1024) {
    u32 idx = (u32)(~kb[p]);
    sb[p] = bx[idx];
    flag[p] = (p < K) ? (unsigned char)0 : (unsigned char)1;
  }
  __syncthreads();

  for (int i = 0; i < K; ++i) {
    if (flag[i]) continue;
    float4 bi = sb[i];
    float area_i = (bi.z - bi.x) * (bi.w - bi.y);
    for (int j = i + 1 + t; j < K; j += 1024) {
      float4 bj = sb[j];
      float lx = fmaxf(bi.x, bj.x);
      float ly = fmaxf(bi.y, bj.y);
      float rx = fminf(bi.z, bj.z);
      float ry = fminf(bi.w, bj.w);
      float iw = fmaxf(rx - lx, 0.0f);
      float ih = fmaxf(ry - ly, 0.0f);
      float inter = iw * ih;
      float area_j = (bj.z - bj.x) * (bj.w - bj.y);
      float iou = inter / (area_i + area_j - inter);
      if (iou > 0.5f) flag[j] = (unsigned char)1;
    }
    __syncthreads();
  }

  float4* oboxes = (float4*)(out) + (size_t)b * NB;
  float* oscores = out + (size_t)BIMG * NB * 4 + (size_t)b * NB;
  float* okeep   = out + (size_t)BIMG * NB * 5 + (size_t)b * NB;
  const float* pb = prob + (size_t)b * NB;
  for (int p = t; p < NB; p += 1024) {
    bool kp = (p < K) && (flag[p] == 0);
    float4 bv = sb[p];
    if (!kp) { bv.x = 0.0f; bv.y = 0.0f; bv.z = 0.0f; bv.w = 0.0f; }
    oboxes[p] = bv;
    u32 idx = (u32)(~kb[p]);
    oscores[p] = kp ? pb[idx] : 0.0f;
    okeep[p] = kp ? 1.0f : 0.0f;
  }
}

// ---------------------------------------------------------------------------
extern "C" void kernel_launch(void* const* d_in, const int* in_sizes, int n_in,
                              void* d_out, int out_size, void* d_ws, size_t ws_size,
                              hipStream_t stream) {
  const float* offsets = (const float*)d_in[0];   // [B,N,4] f32
  const float* labels  = (const float*)d_in[1];   // [B,N,1] f32
  const float* anchors = (const float*)d_in[2];   // [N,4]   f32
  float* out = (float*)d_out;

  char* ws = (char*)d_ws;
  u32*    kcount = (u32*)(ws + WS_KCOUNT);
  u64*    keys   = (u64*)(ws + WS_KEYS);
  float4* boxes  = (float4*)(ws + WS_BOXES);
  float*  prob   = (float*)(ws + WS_PROB);
  float4* sboxes = (float4*)(ws + WS_SBOXES);
  float*  sprob  = (float*)(ws + WS_SPROB);

  int total = BIMG * NB;
  decode_kernel<<<(total + 255) / 256, 256, 0, stream>>>(
      offsets, labels, anchors, keys, boxes, prob);

  sort_kernel<<<BIMG, 1024, 0, stream>>>(keys, boxes, prob, sboxes, sprob, kcount);

  if (ws_size >= WS_NEEDED) {
    u64*    remv   = (u64*)(ws + WS_REMV);
    u64*    mask   = (u64*)(ws + WS_MASK);
    unsigned char* rownz = (unsigned char*)(ws + WS_ROWNZ);

    mask_kernel<<<dim3(NB, BIMG), 256, 0, stream>>>(sboxes, kcount, mask, rownz);

    scan_kernel<<<BIMG, 64, 0, stream>>>(mask, rownz, kcount, remv);

    output_kernel<<<(total + 255) / 256, 256, 0, stream>>>(
        sboxes, sprob, remv, kcount, out);
  } else {
    nms_kernel<<<BIMG, 1024, 0, stream>>>(keys, boxes, prob, kcount, out);
  }
}